// Round 7
// baseline (528.774 us; speedup 1.0000x reference)
//
#include <hip/hip_runtime.h>
#include <math.h>

#define NN 50000
#define NE 500000
#define HIDS 128
#define MCOLS 896   // q(256) k(256) v(256) skip(128)
#define NLAYERS 3

typedef __attribute__((ext_vector_type(8))) short short8;
typedef __attribute__((ext_vector_type(4))) float floatx4;
typedef _Float16 half8v __attribute__((ext_vector_type(8)));
typedef _Float16 half2v __attribute__((ext_vector_type(2)));

union H2U { half8v v; half2v h[4]; };

#define BSTR 152    // B-tile LDS row stride in shorts (proven conflict-benign in R2-R6)

// ---------- helpers ----------
static __device__ __forceinline__ unsigned short f2bf(float f) {
    unsigned u = __float_as_uint(f);
    u += 0x7fffu + ((u >> 16) & 1u);   // RNE
    return (unsigned short)(u >> 16);
}
static __device__ __forceinline__ unsigned short f2h(float f) {
    union { _Float16 h; unsigned short u; } c;
    c.h = (_Float16)f;
    return c.u;
}
static __device__ __forceinline__ float fexp2(float x) {
    float r;
    asm("v_exp_f32 %0, %1" : "=v"(r) : "v"(x));
    return r;
}
// VALU-rate width-16 sum via DPP: xor1, xor2 (quad_perm), ror4, ror8 (row rotate).
#define DPP_ADD(v, ctrl) \
    v += __int_as_float(__builtin_amdgcn_mov_dpp(__float_as_int(v), ctrl, 0xf, 0xf, true))
static __device__ __forceinline__ float wred16(float v) {
    DPP_ADD(v, 0xB1);    // quad_perm [1,0,3,2]  : lane ^ 1
    DPP_ADD(v, 0x4E);    // quad_perm [2,3,0,1]  : lane ^ 2
    DPP_ADD(v, 0x124);   // row_ror:4            : quad rotate
    DPP_ADD(v, 0x128);   // row_ror:8            : half-row rotate
    return v;
}
static __device__ __forceinline__ float wred64(float v) {
    v += __shfl_xor(v, 1, 64);
    v += __shfl_xor(v, 2, 64);
    v += __shfl_xor(v, 4, 64);
    v += __shfl_xor(v, 8, 64);
    v += __shfl_xor(v, 16, 64);
    v += __shfl_xor(v, 32, 64);
    return v;
}

// ---------- CSR build ----------
__global__ __launch_bounds__(1024) void eatb_count(const int* __restrict__ tgt, int* __restrict__ cnt) {
    int e = blockIdx.x * 1024 + threadIdx.x;
    if (e < NE) atomicAdd(&cnt[tgt[e]], 1);
}

__global__ __launch_bounds__(256) void eatb_blocksum(const int* __restrict__ cnt, int* __restrict__ bsums) {
    __shared__ int sm[256];
    int i = blockIdx.x * 256 + threadIdx.x;
    sm[threadIdx.x] = (i < NN) ? cnt[i] : 0;
    __syncthreads();
    for (int off = 128; off > 0; off >>= 1) {
        if (threadIdx.x < off) sm[threadIdx.x] += sm[threadIdx.x + off];
        __syncthreads();
    }
    if (threadIdx.x == 0) bsums[blockIdx.x] = sm[0];
}

__global__ __launch_bounds__(256) void eatb_scanb(int* __restrict__ bsums, int nb) {
    __shared__ int sm[256];
    int t = threadIdx.x;
    int v = (t < nb) ? bsums[t] : 0;
    sm[t] = v;
    __syncthreads();
    for (int off = 1; off < 256; off <<= 1) {
        int x = (t >= off) ? sm[t - off] : 0;
        __syncthreads();
        sm[t] += x;
        __syncthreads();
    }
    if (t < nb) bsums[t] = sm[t] - v;   // exclusive
}

__global__ __launch_bounds__(256) void eatb_rowstart(const int* __restrict__ cnt, const int* __restrict__ bsums,
                                                     int* __restrict__ row_start) {
    __shared__ int sm[256];
    int t = threadIdx.x;
    int i = blockIdx.x * 256 + t;
    int v = (i < NN) ? cnt[i] : 0;
    sm[t] = v;
    __syncthreads();
    for (int off = 1; off < 256; off <<= 1) {
        int x = (t >= off) ? sm[t - off] : 0;
        __syncthreads();
        sm[t] += x;
        __syncthreads();
    }
    int excl = sm[t] - v + bsums[blockIdx.x];
    if (i < NN) row_start[i] = excl;
}

// scatter atomicAdds on row_start itself: afterwards row_start[n] == END of row n
__global__ __launch_bounds__(1024) void eatb_scatter(const int* __restrict__ src, const int* __restrict__ tgt,
                                                     const float* __restrict__ ea, int* __restrict__ row_state,
                                                     int2* __restrict__ csr) {
    int e = blockIdx.x * 1024 + threadIdx.x;
    if (e >= NE) return;
    int t = tgt[e];
    int pos = atomicAdd(&row_state[t], 1);
    int2 val;
    val.x = src[e];
    val.y = __float_as_int(ea[e]);
    csr[pos] = val;
}

// ---------- pack transposed bf16 weights: WcatT[l][c=0..895][k=0..127] ----------
// q columns (c<256) are pre-scaled by (1/sqrt(128))*log2(e): attention scores come
// out of the GEMM directly in exp2 units -> attn uses raw v_exp_f32, no muls.
__global__ __launch_bounds__(256) void eatb_packw(const float* __restrict__ Wq, const float* __restrict__ Wk,
                                                  const float* __restrict__ Wv, const float* __restrict__ Ws,
                                                  const float* __restrict__ bq, const float* __restrict__ bk,
                                                  const float* __restrict__ bv, const float* __restrict__ bs,
                                                  unsigned short* __restrict__ Wt, float* __restrict__ bcat) {
    const float QS = 0.08838834764831845f * 1.4426950408889634f;  // rs * log2(e)
    int idx = blockIdx.x * 256 + threadIdx.x;
    const int WTOT = NLAYERS * MCOLS * HIDS;
    if (idx < WTOT) {
        int l = idx / (MCOLS * HIDS);
        int rem = idx % (MCOLS * HIDS);
        int c = rem / HIDS, k = rem % HIDS;
        float v;
        if (c < 256)      v = Wq[(l * HIDS + k) * 256 + c] * QS;
        else if (c < 512) v = Wk[(l * HIDS + k) * 256 + c - 256];
        else if (c < 768) v = Wv[(l * HIDS + k) * 256 + c - 512];
        else              v = Ws[(l * HIDS + k) * 128 + c - 768];
        Wt[idx] = f2bf(v);
    } else {
        int i2 = idx - WTOT;
        if (i2 < NLAYERS * MCOLS) {
            int l = i2 / MCOLS, c = i2 % MCOLS;
            float v;
            if (c < 256)      v = bq[l * 256 + c] * QS;
            else if (c < 512) v = bk[l * 256 + c - 256];
            else if (c < 768) v = bv[l * 256 + c - 512];
            else              v = bs[l * 128 + c - 768];
            bcat[i2] = v;
        }
    }
}

// ---------- input layernorm (wave per node) -> fp32 xcur + bf16 xb ----------
__global__ __launch_bounds__(256) void eatb_ln_in(const float* __restrict__ x, const float* __restrict__ g,
                                                  const float* __restrict__ b, float* __restrict__ xout,
                                                  unsigned short* __restrict__ xb) {
    int wid = threadIdx.x >> 6, lane = threadIdx.x & 63;
    int n = blockIdx.x * 4 + wid;
    if (n >= NN) return;
    float2 v = *(const float2*)(x + (size_t)n * HIDS + 2 * lane);
    float mu = wred64(v.x + v.y) * (1.f / 128.f);
    float cx = v.x - mu, cy = v.y - mu;
    float var = wred64(cx * cx + cy * cy) * (1.f / 128.f);
    float r = rsqrtf(var + 1e-5f);
    float2 g2 = *(const float2*)(g + 2 * lane);
    float2 b2 = *(const float2*)(b + 2 * lane);
    float2 o;
    o.x = cx * r * g2.x + b2.x;
    o.y = cy * r * g2.y + b2.y;
    *(float2*)(xout + (size_t)n * HIDS + 2 * lane) = o;
    unsigned pk = (unsigned)f2bf(o.x) | ((unsigned)f2bf(o.y) << 16);
    *(unsigned*)(xb + (size_t)n * HIDS + 2 * lane) = pk;
}

// ---------- bf16 MFMA GEMM: A in registers (loop-invariant), B via LDS per col-tile ----------
// R7: M-tile 64, 256 threads (4 waves x 16 rows). LDS 19456+17408=36864 B -> 4 blocks/CU
// (was 128-row/512-thr/54KB -> 2 blocks/CU with a 391-block imbalance tail: 135 CUs x1
// block vs 128 CUs x2). Grid 782 ~ 3.05 blocks/CU, balanced; more barrier overlap.
__global__ __launch_bounds__(256) void eatb_gemm(const unsigned short* __restrict__ xb,
                                                 const unsigned short* __restrict__ Wt,
                                                 const float* __restrict__ bias,
                                                 unsigned short* __restrict__ qpack,
                                                 unsigned short* __restrict__ kvpack,
                                                 unsigned short* __restrict__ skipbuf) {
    __shared__ __align__(16) short Bs[64 * BSTR];   // 19456 B
    __shared__ __align__(16) float Cs[64 * 68];     // 17408 B

    int tid = threadIdx.x;
    int r0 = blockIdx.x * 64;
    int wid = tid >> 6, lane = tid & 63;
    int fr = lane & 15;
    int kq = (lane >> 4) * 8;

    // A fragments: row r0 + wid*16 + fr (4 waves x 16 rows = 64); loop-invariant (16 VGPRs)
    int ar = r0 + wid * 16 + fr;
    bool aok = ar < NN;
    const unsigned short* aptr = xb + (size_t)(aok ? ar : 0) * HIDS;
    short8 afk[4];
    #pragma unroll
    for (int ks = 0; ks < 4; ++ks) afk[ks] = *(const short8*)(aptr + ks * 32 + kq);
    if (!aok) {
        short8 z = {};
        afk[0] = z; afk[1] = z; afk[2] = z; afk[3] = z;
    }

    // stage B tile 0: 256 thr x 64 B (4 passes of 16B)
    int brow = tid >> 4, bch = (tid & 15) * 8;
    #pragma unroll
    for (int p = 0; p < 4; ++p) {
        int r = brow + p * 16;
        *(uint4*)(Bs + r * BSTR + bch) = *(const uint4*)(Wt + (size_t)r * HIDS + bch);
    }
    __syncthreads();

    int cl = (tid & 15) * 4;
    for (int ci = 0; ci < 14; ++ci) {
        floatx4 acc[4] = {};
        #pragma unroll
        for (int ks = 0; ks < 4; ++ks) {
            int kof = ks * 32 + kq;
            #pragma unroll
            for (int n = 0; n < 4; ++n) {
                short8 bf = *(const short8*)(Bs + (n * 16 + fr) * BSTR + kof);
                acc[n] = __builtin_amdgcn_mfma_f32_16x16x32_bf16(afk[ks], bf, acc[n], 0, 0, 0);
            }
        }
        // C fragments -> LDS (C/D map: col=lane&15, row=(lane>>4)*4+rg  [m89])
        #pragma unroll
        for (int n = 0; n < 4; ++n)
            #pragma unroll
            for (int rg = 0; rg < 4; ++rg)
                Cs[(wid * 16 + (lane >> 4) * 4 + rg) * 68 + n * 16 + fr] = acc[n][rg];
        __syncthreads();   // all Bs reads + Cs writes complete

        // epilogue (reads Cs) + stage next B (writes Bs) — disjoint LDS, overlap
        int c0 = ci * 64;
        int C = c0 + cl;
        float4 b4 = *(const float4*)(bias + C);
        #pragma unroll
        for (int p = 0; p < 4; ++p) {
            int rr = (tid >> 4) + 16 * p;
            int gr = r0 + rr;
            if (gr < NN) {
                float4 cv = *(const float4*)(Cs + rr * 68 + cl);
                ushort4 o;
                o.x = f2h(cv.x + b4.x);
                o.y = f2h(cv.y + b4.y);
                o.z = f2h(cv.z + b4.z);
                o.w = f2h(cv.w + b4.w);
                if (C < 256)      *(ushort4*)(qpack + (size_t)gr * 256 + C) = o;
                else if (C < 768) *(ushort4*)(kvpack + (size_t)gr * 512 + (C - 256)) = o;
                else              *(ushort4*)(skipbuf + (size_t)gr * 128 + (C - 768)) = o;
            }
        }
        if (ci < 13) {
            #pragma unroll
            for (int p = 0; p < 4; ++p) {
                int r = brow + p * 16;
                *(uint4*)(Bs + r * BSTR + bch) = *(const uint4*)(Wt + (size_t)((ci + 1) * 64 + r) * HIDS + bch);
            }
        }
        __syncthreads();   // Cs free; new Bs visible
    }
}

// ---------- fused attention + epilogue: one wave per target node ----------
// lane map: slot = lane>>5 (edge slot), h = (lane>>4)&1, sl = lane&15 (dims sl*8..sl*8+7)
// 8 edges per iteration (4 per slot); csr prefetched one iter ahead. FROZEN since R6:
// three MLP probes (R1/R5/R6) netted ~+3%; mixed VALU(59%)/latency regime, per-wave
// MLP depth not extractable at source level (VGPR=48 shows loads sink to uses).
// PV accumulate in f32 (w unbounded under no-max softmax -> f16 w overflows; R3 lesson).
// No min-waves bound (R4: (256,6) caused spill, WRITE 37.5->175 MB).
__global__ __launch_bounds__(256) void eatb_attn(const unsigned short* __restrict__ qpack,
                                                 const unsigned short* __restrict__ kvpack,
                                                 const unsigned short* __restrict__ skipbuf,
                                                 const int2* __restrict__ csr, const int* __restrict__ row_state,
                                                 const float* __restrict__ Wel, const float* __restrict__ g,
                                                 const float* __restrict__ beta, const float* __restrict__ xcur,
                                                 float* __restrict__ dst, unsigned short* __restrict__ xbout) {
    int wid = threadIdx.x >> 6;
    int lane = threadIdx.x & 63;
    int n = blockIdx.x * 4 + wid;
    if (n >= NN) return;
    int slot = lane >> 5;
    int h = (lane >> 4) & 1;
    int sl = lane & 15;
    int dbase = sl * 8;

    const _Float16* qh16 = (const _Float16*)qpack;
    const _Float16* kvh = (const _Float16*)kvpack;

    half8v qh = *(const half8v*)(qh16 + n * 256 + h * 128 + dbase);
    H2U qq; qq.v = qh;
    const float* wep = Wel + h * 128 + dbase;
    float qwe;
    {
        float4 wa = *(const float4*)wep;
        float4 wb = *(const float4*)(wep + 4);
        qwe = wred16((float)qh[0] * wa.x + (float)qh[1] * wa.y + (float)qh[2] * wa.z + (float)qh[3] * wa.w +
                     (float)qh[4] * wb.x + (float)qh[5] * wb.y + (float)qh[6] * wb.z + (float)qh[7] * wb.w);
    }

    float s0 = 0.f, s1 = 0.f, sea0 = 0.f, sea1 = 0.f;
    float a0[8] = {0.f, 0.f, 0.f, 0.f, 0.f, 0.f, 0.f, 0.f};   // A+C bank
    float a1[8] = {0.f, 0.f, 0.f, 0.f, 0.f, 0.f, 0.f, 0.f};   // B+D bank

    int end = row_state[n];
    int beg = (n > 0) ? row_state[n - 1] : 0;
    int nit = (end - beg + 7) >> 3;
    int lbase = (h << 7) + (sl << 3);        // 32-bit offsets -> saddr-form loads

    int2 cA, cB, cC, cD;
    if (nit > 0) {
        int e = beg + slot;
        cA = csr[(e < end) ? e : beg];
        cB = csr[(e + 2 < end) ? e + 2 : beg];
        cC = csr[(e + 4 < end) ? e + 4 : beg];
        cD = csr[(e + 6 < end) ? e + 6 : beg];
    }

    for (int it = 0; it < nit; ++it) {
        int ebase = beg + 8 * it + slot;
        bool vA = ebase < end, vB = ebase + 2 < end, vC = ebase + 4 < end, vD = ebase + 6 < end;
        float eaA = __int_as_float(cA.y);
        float eaB = __int_as_float(cB.y);
        float eaC = __int_as_float(cC.y);
        float eaD = __int_as_float(cD.y);
        int koA = (cA.x << 9) + lbase;
        int koB = (cB.x << 9) + lbase;
        int koC = (cC.x << 9) + lbase;
        int koD = (cD.x << 9) + lbase;
        // issue all 8 gathers back-to-back (k's first: score path unblocks earliest)
        half8v kA = *(const half8v*)(kvh + koA);
        half8v kB = *(const half8v*)(kvh + koB);
        half8v kC = *(const half8v*)(kvh + koC);
        half8v kD = *(const half8v*)(kvh + koD);
        half8v vA8 = *(const half8v*)(kvh + koA + 256);
        half8v vB8 = *(const half8v*)(kvh + koB + 256);
        half8v vC8 = *(const half8v*)(kvh + koC + 256);
        half8v vD8 = *(const half8v*)(kvh + koD + 256);
        __builtin_amdgcn_sched_barrier(0);
        // prefetch next iteration's csr while gathers are in flight
        if (it + 1 < nit) {
            int e2 = ebase + 8;
            cA = csr[(e2 < end) ? e2 : beg];
            cB = csr[(e2 + 2 < end) ? e2 + 2 : beg];
            cC = csr[(e2 + 4 < end) ? e2 + 4 : beg];
            cD = csr[(e2 + 6 < end) ? e2 + 6 : beg];
        }

        H2U ka, kb, kc, kd;
        ka.v = kA; kb.v = kB; kc.v = kC; kd.v = kD;
        float dA0 = __builtin_amdgcn_fdot2(qq.h[0], ka.h[0], 0.f, false);
        float dA1 = __builtin_amdgcn_fdot2(qq.h[1], ka.h[1], 0.f, false);
        dA0 = __builtin_amdgcn_fdot2(qq.h[2], ka.h[2], dA0, false);
        dA1 = __builtin_amdgcn_fdot2(qq.h[3], ka.h[3], dA1, false);
        float dB0 = __builtin_amdgcn_fdot2(qq.h[0], kb.h[0], 0.f, false);
        float dB1 = __builtin_amdgcn_fdot2(qq.h[1], kb.h[1], 0.f, false);
        dB0 = __builtin_amdgcn_fdot2(qq.h[2], kb.h[2], dB0, false);
        dB1 = __builtin_amdgcn_fdot2(qq.h[3], kb.h[3], dB1, false);
        float dC0 = __builtin_amdgcn_fdot2(qq.h[0], kc.h[0], 0.f, false);
        float dC1 = __builtin_amdgcn_fdot2(qq.h[1], kc.h[1], 0.f, false);
        dC0 = __builtin_amdgcn_fdot2(qq.h[2], kc.h[2], dC0, false);
        dC1 = __builtin_amdgcn_fdot2(qq.h[3], kc.h[3], dC1, false);
        float dD0 = __builtin_amdgcn_fdot2(qq.h[0], kd.h[0], 0.f, false);
        float dD1 = __builtin_amdgcn_fdot2(qq.h[1], kd.h[1], 0.f, false);
        dD0 = __builtin_amdgcn_fdot2(qq.h[2], kd.h[2], dD0, false);
        dD1 = __builtin_amdgcn_fdot2(qq.h[3], kd.h[3], dD1, false);
        float pA = wred16(dA0 + dA1);
        float pB = wred16(dB0 + dB1);
        float pC = wred16(dC0 + dC1);
        float pD = wred16(dD0 + dD1);
        float wA = vA ? fexp2(fmaf(eaA, qwe, pA)) : 0.f;
        float wB = vB ? fexp2(fmaf(eaB, qwe, pB)) : 0.f;
        float wC = vC ? fexp2(fmaf(eaC, qwe, pC)) : 0.f;
        float wD = vD ? fexp2(fmaf(eaD, qwe, pD)) : 0.f;
        s0 += wA; s1 += wB; s0 += wC; s1 += wD;
        sea0 = fmaf(wA, eaA, sea0);
        sea1 = fmaf(wB, eaB, sea1);
        sea0 = fmaf(wC, eaC, sea0);
        sea1 = fmaf(wD, eaD, sea1);
        // PV accumulate: f32 fmaf (compiler emits v_fma_mix with f16 v), two banks
        #pragma unroll
        for (int d = 0; d < 8; ++d) {
            a0[d] = fmaf(wA, (float)vA8[d], a0[d]);
            a1[d] = fmaf(wB, (float)vB8[d], a1[d]);
            a0[d] = fmaf(wC, (float)vC8[d], a0[d]);
            a1[d] = fmaf(wD, (float)vD8[d], a1[d]);
        }
    }

    float s = s0 + s1, sea = sea0 + sea1;
    float o0 = a0[0] + a1[0], o1 = a0[1] + a1[1], o2 = a0[2] + a1[2], o3 = a0[3] + a1[3];
    float o4 = a0[4] + a1[4], o5 = a0[5] + a1[5], o6 = a0[6] + a1[6], o7 = a0[7] + a1[7];

    // merge the two edge slots (lane ^ 32): plain sums
    s += __shfl_xor(s, 32, 64);
    sea += __shfl_xor(sea, 32, 64);
    o0 += __shfl_xor(o0, 32, 64);
    o1 += __shfl_xor(o1, 32, 64);
    o2 += __shfl_xor(o2, 32, 64);
    o3 += __shfl_xor(o3, 32, 64);
    o4 += __shfl_xor(o4, 32, 64);
    o5 += __shfl_xor(o5, 32, 64);
    o6 += __shfl_xor(o6, 32, 64);
    o7 += __shfl_xor(o7, 32, 64);

    float4 wea = *(const float4*)wep;
    float4 web = *(const float4*)(wep + 4);

    float inv = (s > 0.f) ? 1.f / s : 1.f;
    float sw = sea * inv;
    o0 = o0 * inv + sw * wea.x;
    o1 = o1 * inv + sw * wea.y;
    o2 = o2 * inv + sw * wea.z;
    o3 = o3 * inv + sw * wea.w;
    o4 = o4 * inv + sw * web.x;
    o5 = o5 * inv + sw * web.y;
    o6 = o6 * inv + sw * web.z;
    o7 = o7 * inv + sw * web.w;
    // head mean (h <-> h^1 is lane ^ 16)
    o0 = 0.5f * (o0 + __shfl_xor(o0, 16, 64));
    o1 = 0.5f * (o1 + __shfl_xor(o1, 16, 64));
    o2 = 0.5f * (o2 + __shfl_xor(o2, 16, 64));
    o3 = 0.5f * (o3 + __shfl_xor(o3, 16, 64));
    o4 = 0.5f * (o4 + __shfl_xor(o4, 16, 64));
    o5 = 0.5f * (o5 + __shfl_xor(o5, 16, 64));
    o6 = 0.5f * (o6 + __shfl_xor(o6, 16, 64));
    o7 = 0.5f * (o7 + __shfl_xor(o7, 16, 64));

    // + skip (f16), ELU, residual, LN (dims dbase..dbase+7; 4x redundant across (slot,h))
    const _Float16* skp = (const _Float16*)skipbuf + n * 128 + dbase;
    half8v skh = *(const half8v*)skp;
    const float* xrp = xcur + n * 128 + dbase;
    float4 xra = *(const float4*)xrp, xrb = *(const float4*)(xrp + 4);
    float y0 = o0 + (float)skh[0], y1 = o1 + (float)skh[1], y2 = o2 + (float)skh[2], y3 = o3 + (float)skh[3];
    float y4 = o4 + (float)skh[4], y5 = o5 + (float)skh[5], y6 = o6 + (float)skh[6], y7 = o7 + (float)skh[7];
    y0 = (y0 > 0.f) ? y0 : __expf(y0) - 1.f;
    y1 = (y1 > 0.f) ? y1 : __expf(y1) - 1.f;
    y2 = (y2 > 0.f) ? y2 : __expf(y2) - 1.f;
    y3 = (y3 > 0.f) ? y3 : __expf(y3) - 1.f;
    y4 = (y4 > 0.f) ? y4 : __expf(y4) - 1.f;
    y5 = (y5 > 0.f) ? y5 : __expf(y5) - 1.f;
    y6 = (y6 > 0.f) ? y6 : __expf(y6) - 1.f;
    y7 = (y7 > 0.f) ? y7 : __expf(y7) - 1.f;
    float p0 = xra.x + y0, p1 = xra.y + y1, p2 = xra.z + y2, p3 = xra.w + y3;
    float p4 = xrb.x + y4, p5 = xrb.y + y5, p6 = xrb.z + y6, p7 = xrb.w + y7;
    float mu = wred16(p0 + p1 + p2 + p3 + p4 + p5 + p6 + p7) * (1.f / 128.f);
    float c0 = p0 - mu, c1 = p1 - mu, c2 = p2 - mu, c3 = p3 - mu;
    float c4 = p4 - mu, c5 = p5 - mu, c6 = p6 - mu, c7 = p7 - mu;
    float var = wred16(c0 * c0 + c1 * c1 + c2 * c2 + c3 * c3 +
                       c4 * c4 + c5 * c5 + c6 * c6 + c7 * c7) * (1.f / 128.f);
    float r = rsqrtf(var + 1e-5f);
    if (lane < 16) {
        const float* gp = g + dbase;
        const float* bp = beta + dbase;
        float4 ga = *(const float4*)gp, gb = *(const float4*)(gp + 4);
        float4 ba = *(const float4*)bp, bb = *(const float4*)(bp + 4);
        float4 oa, ob;
        oa.x = c0 * r * ga.x + ba.x; oa.y = c1 * r * ga.y + ba.y;
        oa.z = c2 * r * ga.z + ba.z; oa.w = c3 * r * ga.w + ba.w;
        ob.x = c4 * r * gb.x + bb.x; ob.y = c5 * r * gb.y + bb.y;
        ob.z = c6 * r * gb.z + bb.z; ob.w = c7 * r * gb.w + bb.w;
        float* dp = dst + n * 128 + dbase;
        *(float4*)dp = oa;
        *(float4*)(dp + 4) = ob;
        if (xbout) {
            uint4 pk;
            pk.x = (unsigned)f2bf(oa.x) | ((unsigned)f2bf(oa.y) << 16);
            pk.y = (unsigned)f2bf(oa.z) | ((unsigned)f2bf(oa.w) << 16);
            pk.z = (unsigned)f2bf(ob.x) | ((unsigned)f2bf(ob.y) << 16);
            pk.w = (unsigned)f2bf(ob.z) | ((unsigned)f2bf(ob.w) << 16);
            *(uint4*)(xbout + n * 128 + dbase) = pk;
        }
    }
}

// ---------- launch ----------
extern "C" void kernel_launch(void* const* d_in, const int* in_sizes, int n_in,
                              void* d_out, int out_size, void* d_ws, size_t ws_size,
                              hipStream_t stream) {
    const float* x       = (const float*)d_in[0];
    const int*   ei      = (const int*)d_in[1];
    const float* eattr   = (const float*)d_in[2];
    const float* ln_in_g = (const float*)d_in[3];
    const float* ln_in_b = (const float*)d_in[4];
    const float* Wq = (const float*)d_in[5];
    const float* bq = (const float*)d_in[6];
    const float* Wk = (const float*)d_in[7];
    const float* bk = (const float*)d_in[8];
    const float* Wv = (const float*)d_in[9];
    const float* bv = (const float*)d_in[10];
    const float* We = (const float*)d_in[11];
    const float* Ws = (const float*)d_in[12];
    const float* bs = (const float*)d_in[13];
    const float* ln_g = (const float*)d_in[14];
    const float* ln_b = (const float*)d_in[15];
    float* out = (float*)d_out;

    char* p = (char*)d_ws;
    auto carve = [&](size_t bytes) {
        char* r = p;
        p += (bytes + 255) & ~(size_t)255;
        return (void*)r;
    };
    int*  cnt       = (int*)carve((size_t)NN * 4);
    int*  row_state = (int*)carve((size_t)NN * 4);
    int*  bsums     = (int*)carve(1024);
    int2* csr       = (int2*)carve((size_t)NE * 8);
    unsigned short* WcatT = (unsigned short*)carve((size_t)NLAYERS * MCOLS * HIDS * 2);
    float* bcat     = (float*)carve((size_t)NLAYERS * MCOLS * 4);
    float* xcur     = (float*)carve((size_t)NN * HIDS * 4);
    unsigned short* qpack  = (unsigned short*)carve((size_t)NN * 256 * 2);
    unsigned short* kvpack = (unsigned short*)carve((size_t)NN * 512 * 2);
    unsigned short* skipbuf = (unsigned short*)carve((size_t)NN * HIDS * 2);
    unsigned short* xb = (unsigned short*)carve((size_t)NN * HIDS * 2);

    const int NB_N = (NN + 255) / 256;        // 196
    const int NB_E1K = (NE + 1023) / 1024;    // 489
    const int NODE_BLOCKS = (NN + 3) / 4;     // 12500

    // CSR build (edge_index layout: src = ei[0:E], tgt = ei[E:2E])
    hipMemsetAsync(cnt, 0, (size_t)NN * 4, stream);
    eatb_count<<<NB_E1K, 1024, 0, stream>>>(ei + NE, cnt);
    eatb_blocksum<<<NB_N, 256, 0, stream>>>(cnt, bsums);
    eatb_scanb<<<1, 256, 0, stream>>>(bsums, NB_N);
    eatb_rowstart<<<NB_N, 256, 0, stream>>>(cnt, bsums, row_state);
    eatb_scatter<<<NB_E1K, 1024, 0, stream>>>(ei, ei + NE, eattr, row_state, csr);

    // pack weights (transposed bf16, q pre-scaled) + biases
    {
        int tot = NLAYERS * MCOLS * HIDS + NLAYERS * MCOLS;
        eatb_packw<<<(tot + 255) / 256, 256, 0, stream>>>(Wq, Wk, Wv, Ws, bq, bk, bv, bs, WcatT, bcat);
    }

    // input layernorm -> xcur (fp32) + bf16 xb
    eatb_ln_in<<<NODE_BLOCKS, 256, 0, stream>>>(x, ln_in_g, ln_in_b, xcur, xb);

    // layers
    const int GEMM_BLOCKS = (NN + 63) / 64;   // 782
    for (int l = 0; l < NLAYERS; ++l) {
        eatb_gemm<<<GEMM_BLOCKS, 256, 0, stream>>>(xb, WcatT + (size_t)l * MCOLS * HIDS,
                                                   bcat + (size_t)l * MCOLS, qpack, kvpack, skipbuf);
        float* dst = (l == NLAYERS - 1) ? out : xcur;
        unsigned short* xbo = (l == NLAYERS - 1) ? nullptr : xb;
        eatb_attn<<<NODE_BLOCKS, 256, 0, stream>>>(qpack, kvpack, skipbuf, csr, row_state,
                                                   We + (size_t)l * 256, ln_g + (size_t)l * 128,
                                                   ln_b + (size_t)l * 128, xcur, dst, xbo);
    }
    (void)in_sizes; (void)n_in; (void)out_size; (void)ws_size;
}

// Round 8
// 498.237 us; speedup vs baseline: 1.0613x; 1.0613x over previous
//
#include <hip/hip_runtime.h>
#include <math.h>

#define NN 50000
#define NE 500000
#define HIDS 128
#define MCOLS 896   // q(256) k(256) v(256) skip(128)
#define NLAYERS 3

typedef __attribute__((ext_vector_type(8))) short short8;
typedef __attribute__((ext_vector_type(4))) float floatx4;
typedef _Float16 half8v __attribute__((ext_vector_type(8)));
typedef _Float16 half2v __attribute__((ext_vector_type(2)));

union H2U { half8v v; half2v h[4]; };

#define BSTR 152    // B-tile LDS row stride in shorts (proven conflict-benign)

// fused-kernel grid partitions
#define LNB   12500                 // ln_in blocks (4 nodes/blk)
#define CNTB  1954                  // count blocks (256 edges/blk)
#define PKWB  1355                  // packw blocks (256 elems/blk)
#define GEMM_BLOCKS 782             // 64-row M-tiles

// ---------- helpers ----------
static __device__ __forceinline__ unsigned short f2bf(float f) {
    unsigned u = __float_as_uint(f);
    u += 0x7fffu + ((u >> 16) & 1u);   // RNE
    return (unsigned short)(u >> 16);
}
static __device__ __forceinline__ unsigned short f2h(float f) {
    union { _Float16 h; unsigned short u; } c;
    c.h = (_Float16)f;
    return c.u;
}
static __device__ __forceinline__ float fexp2(float x) {
    float r;
    asm("v_exp_f32 %0, %1" : "=v"(r) : "v"(x));
    return r;
}
// VALU-rate width-16 sum via DPP: xor1, xor2 (quad_perm), ror4, ror8 (row rotate).
#define DPP_ADD(v, ctrl) \
    v += __int_as_float(__builtin_amdgcn_mov_dpp(__float_as_int(v), ctrl, 0xf, 0xf, true))
static __device__ __forceinline__ float wred16(float v) {
    DPP_ADD(v, 0xB1);    // quad_perm [1,0,3,2]  : lane ^ 1
    DPP_ADD(v, 0x4E);    // quad_perm [2,3,0,1]  : lane ^ 2
    DPP_ADD(v, 0x124);   // row_ror:4            : quad rotate
    DPP_ADD(v, 0x128);   // row_ror:8            : half-row rotate
    return v;
}
static __device__ __forceinline__ float wred64(float v) {
    v += __shfl_xor(v, 1, 64);
    v += __shfl_xor(v, 2, 64);
    v += __shfl_xor(v, 4, 64);
    v += __shfl_xor(v, 8, 64);
    v += __shfl_xor(v, 16, 64);
    v += __shfl_xor(v, 32, 64);
    return v;
}

// ---------- fused K_A: ln_in | count | packw (independent jobs, one launch) ----------
__global__ __launch_bounds__(256) void eatb_fuseA(const float* __restrict__ x, const float* __restrict__ lg,
                                                  const float* __restrict__ lb, float* __restrict__ xout,
                                                  unsigned short* __restrict__ xb,
                                                  const int* __restrict__ tgt, int* __restrict__ cnt,
                                                  const float* __restrict__ Wq, const float* __restrict__ Wk,
                                                  const float* __restrict__ Wv, const float* __restrict__ Ws,
                                                  const float* __restrict__ bq, const float* __restrict__ bk,
                                                  const float* __restrict__ bv, const float* __restrict__ bs,
                                                  unsigned short* __restrict__ Wt, float* __restrict__ bcat) {
    int bid = blockIdx.x;
    if (bid < LNB) {
        // ---- input layernorm (wave per node) -> fp32 xcur + bf16 xb ----
        int wid = threadIdx.x >> 6, lane = threadIdx.x & 63;
        int n = bid * 4 + wid;
        if (n >= NN) return;
        float2 v = *(const float2*)(x + (size_t)n * HIDS + 2 * lane);
        float mu = wred64(v.x + v.y) * (1.f / 128.f);
        float cx = v.x - mu, cy = v.y - mu;
        float var = wred64(cx * cx + cy * cy) * (1.f / 128.f);
        float r = rsqrtf(var + 1e-5f);
        float2 g2 = *(const float2*)(lg + 2 * lane);
        float2 b2 = *(const float2*)(lb + 2 * lane);
        float2 o;
        o.x = cx * r * g2.x + b2.x;
        o.y = cy * r * g2.y + b2.y;
        *(float2*)(xout + (size_t)n * HIDS + 2 * lane) = o;
        unsigned pk = (unsigned)f2bf(o.x) | ((unsigned)f2bf(o.y) << 16);
        *(unsigned*)(xb + (size_t)n * HIDS + 2 * lane) = pk;
    } else if (bid < LNB + CNTB) {
        // ---- degree count ----
        int e = (bid - LNB) * 256 + threadIdx.x;
        if (e < NE) atomicAdd(&cnt[tgt[e]], 1);
    } else {
        // ---- pack transposed bf16 weights + biases (q cols pre-scaled by rs*log2e) ----
        const float QS = 0.08838834764831845f * 1.4426950408889634f;
        int idx = (bid - LNB - CNTB) * 256 + threadIdx.x;
        const int WTOT = NLAYERS * MCOLS * HIDS;
        if (idx < WTOT) {
            int l = idx / (MCOLS * HIDS);
            int rem = idx % (MCOLS * HIDS);
            int c = rem / HIDS, k = rem % HIDS;
            float v;
            if (c < 256)      v = Wq[(l * HIDS + k) * 256 + c] * QS;
            else if (c < 512) v = Wk[(l * HIDS + k) * 256 + c - 256];
            else if (c < 768) v = Wv[(l * HIDS + k) * 256 + c - 512];
            else              v = Ws[(l * HIDS + k) * 128 + c - 768];
            Wt[idx] = f2bf(v);
        } else {
            int i2 = idx - WTOT;
            if (i2 < NLAYERS * MCOLS) {
                int l = i2 / MCOLS, c = i2 % MCOLS;
                float v;
                if (c < 256)      v = bq[l * 256 + c] * QS;
                else if (c < 512) v = bk[l * 256 + c - 256];
                else if (c < 768) v = bv[l * 256 + c - 512];
                else              v = bs[l * 128 + c - 768];
                bcat[i2] = v;
            }
        }
    }
}

// ---------- CSR scan (small, serial chain) ----------
__global__ __launch_bounds__(256) void eatb_blocksum(const int* __restrict__ cnt, int* __restrict__ bsums) {
    __shared__ int sm[256];
    int i = blockIdx.x * 256 + threadIdx.x;
    sm[threadIdx.x] = (i < NN) ? cnt[i] : 0;
    __syncthreads();
    for (int off = 128; off > 0; off >>= 1) {
        if (threadIdx.x < off) sm[threadIdx.x] += sm[threadIdx.x + off];
        __syncthreads();
    }
    if (threadIdx.x == 0) bsums[blockIdx.x] = sm[0];
}

__global__ __launch_bounds__(256) void eatb_scanb(int* __restrict__ bsums, int nb) {
    __shared__ int sm[256];
    int t = threadIdx.x;
    int v = (t < nb) ? bsums[t] : 0;
    sm[t] = v;
    __syncthreads();
    for (int off = 1; off < 256; off <<= 1) {
        int x = (t >= off) ? sm[t - off] : 0;
        __syncthreads();
        sm[t] += x;
        __syncthreads();
    }
    if (t < nb) bsums[t] = sm[t] - v;   // exclusive
}

__global__ __launch_bounds__(256) void eatb_rowstart(const int* __restrict__ cnt, const int* __restrict__ bsums,
                                                     int* __restrict__ row_start) {
    __shared__ int sm[256];
    int t = threadIdx.x;
    int i = blockIdx.x * 256 + t;
    int v = (i < NN) ? cnt[i] : 0;
    sm[t] = v;
    __syncthreads();
    for (int off = 1; off < 256; off <<= 1) {
        int x = (t >= off) ? sm[t - off] : 0;
        __syncthreads();
        sm[t] += x;
        __syncthreads();
    }
    int excl = sm[t] - v + bsums[blockIdx.x];
    if (i < NN) row_start[i] = excl;
}

// ---------- GEMM body (R7 64-row tile, 256 thr) as device function ----------
static __device__ __forceinline__ void gemm_body(int bid,
                                                 const unsigned short* __restrict__ xb,
                                                 const unsigned short* __restrict__ Wt,
                                                 const float* __restrict__ bias,
                                                 unsigned short* __restrict__ qpack,
                                                 unsigned short* __restrict__ kvpack,
                                                 unsigned short* __restrict__ skipbuf,
                                                 short* Bs, float* Cs) {
    int tid = threadIdx.x;
    int r0 = bid * 64;
    int wid = tid >> 6, lane = tid & 63;
    int fr = lane & 15;
    int kq = (lane >> 4) * 8;

    int ar = r0 + wid * 16 + fr;
    bool aok = ar < NN;
    const unsigned short* aptr = xb + (size_t)(aok ? ar : 0) * HIDS;
    short8 afk[4];
    #pragma unroll
    for (int ks = 0; ks < 4; ++ks) afk[ks] = *(const short8*)(aptr + ks * 32 + kq);
    if (!aok) {
        short8 z = {};
        afk[0] = z; afk[1] = z; afk[2] = z; afk[3] = z;
    }

    int brow = tid >> 4, bch = (tid & 15) * 8;
    #pragma unroll
    for (int p = 0; p < 4; ++p) {
        int r = brow + p * 16;
        *(uint4*)(Bs + r * BSTR + bch) = *(const uint4*)(Wt + (size_t)r * HIDS + bch);
    }
    __syncthreads();

    int cl = (tid & 15) * 4;
    for (int ci = 0; ci < 14; ++ci) {
        floatx4 acc[4] = {};
        #pragma unroll
        for (int ks = 0; ks < 4; ++ks) {
            int kof = ks * 32 + kq;
            #pragma unroll
            for (int n = 0; n < 4; ++n) {
                short8 bf = *(const short8*)(Bs + (n * 16 + fr) * BSTR + kof);
                acc[n] = __builtin_amdgcn_mfma_f32_16x16x32_bf16(afk[ks], bf, acc[n], 0, 0, 0);
            }
        }
        // C/D map: col=lane&15, row=(lane>>4)*4+rg
        #pragma unroll
        for (int n = 0; n < 4; ++n)
            #pragma unroll
            for (int rg = 0; rg < 4; ++rg)
                Cs[(wid * 16 + (lane >> 4) * 4 + rg) * 68 + n * 16 + fr] = acc[n][rg];
        __syncthreads();

        int c0 = ci * 64;
        int C = c0 + cl;
        float4 b4 = *(const float4*)(bias + C);
        #pragma unroll
        for (int p = 0; p < 4; ++p) {
            int rr = (tid >> 4) + 16 * p;
            int gr = r0 + rr;
            if (gr < NN) {
                float4 cv = *(const float4*)(Cs + rr * 68 + cl);
                ushort4 o;
                o.x = f2h(cv.x + b4.x);
                o.y = f2h(cv.y + b4.y);
                o.z = f2h(cv.z + b4.z);
                o.w = f2h(cv.w + b4.w);
                if (C < 256)      *(ushort4*)(qpack + (size_t)gr * 256 + C) = o;
                else if (C < 768) *(ushort4*)(kvpack + (size_t)gr * 512 + (C - 256)) = o;
                else              *(ushort4*)(skipbuf + (size_t)gr * 128 + (C - 768)) = o;
            }
        }
        if (ci < 13) {
            #pragma unroll
            for (int p = 0; p < 4; ++p) {
                int r = brow + p * 16;
                *(uint4*)(Bs + r * BSTR + bch) = *(const uint4*)(Wt + (size_t)((ci + 1) * 64 + r) * HIDS + bch);
            }
        }
        __syncthreads();
    }
}

// plain GEMM (layers 1,2)
__global__ __launch_bounds__(256) void eatb_gemm(const unsigned short* __restrict__ xb,
                                                 const unsigned short* __restrict__ Wt,
                                                 const float* __restrict__ bias,
                                                 unsigned short* __restrict__ qpack,
                                                 unsigned short* __restrict__ kvpack,
                                                 unsigned short* __restrict__ skipbuf) {
    __shared__ __align__(16) short Bs[64 * BSTR];
    __shared__ __align__(16) float Cs[64 * 68];
    gemm_body(blockIdx.x, xb, Wt, bias, qpack, kvpack, skipbuf, Bs, Cs);
}

// ---------- fused K_E: gemm layer-0 | scatter (independent; scatter hides under gemm) ----------
__global__ __launch_bounds__(256) void eatb_fuseE(const unsigned short* __restrict__ xb,
                                                  const unsigned short* __restrict__ Wt,
                                                  const float* __restrict__ bias,
                                                  unsigned short* __restrict__ qpack,
                                                  unsigned short* __restrict__ kvpack,
                                                  unsigned short* __restrict__ skipbuf,
                                                  const int* __restrict__ src, const int* __restrict__ tgt,
                                                  const float* __restrict__ ea, int* __restrict__ row_state,
                                                  int2* __restrict__ csr) {
    __shared__ __align__(16) short Bs[64 * BSTR];
    __shared__ __align__(16) float Cs[64 * 68];
    int bid = blockIdx.x;
    if (bid < GEMM_BLOCKS) {
        gemm_body(bid, xb, Wt, bias, qpack, kvpack, skipbuf, Bs, Cs);
    } else {
        // scatter: row_state[n] becomes END of row n
        int e = (bid - GEMM_BLOCKS) * 256 + threadIdx.x;
        if (e >= NE) return;
        int t = tgt[e];
        int pos = atomicAdd(&row_state[t], 1);
        int2 val;
        val.x = src[e];
        val.y = __float_as_int(ea[e]);
        csr[pos] = val;
    }
}

// ---------- fused attention + epilogue: one wave per target node (FROZEN since R6) ----------
// lane map: slot = lane>>5 (edge slot), h = (lane>>4)&1, sl = lane&15 (dims sl*8..sl*8+7)
// 8 edges per iteration; csr prefetched one iter ahead. Three MLP probes (R1/R5/R6)
// netted ~+3%; mixed VALU(55%)/latency regime. PV accumulate f32 (R3: f16 w overflows).
// No min-waves bound (R4: (256,6) caused spill).
__global__ __launch_bounds__(256) void eatb_attn(const unsigned short* __restrict__ qpack,
                                                 const unsigned short* __restrict__ kvpack,
                                                 const unsigned short* __restrict__ skipbuf,
                                                 const int2* __restrict__ csr, const int* __restrict__ row_state,
                                                 const float* __restrict__ Wel, const float* __restrict__ g,
                                                 const float* __restrict__ beta, const float* __restrict__ xcur,
                                                 float* __restrict__ dst, unsigned short* __restrict__ xbout) {
    int wid = threadIdx.x >> 6;
    int lane = threadIdx.x & 63;
    int n = blockIdx.x * 4 + wid;
    if (n >= NN) return;
    int slot = lane >> 5;
    int h = (lane >> 4) & 1;
    int sl = lane & 15;
    int dbase = sl * 8;

    const _Float16* qh16 = (const _Float16*)qpack;
    const _Float16* kvh = (const _Float16*)kvpack;

    half8v qh = *(const half8v*)(qh16 + n * 256 + h * 128 + dbase);
    H2U qq; qq.v = qh;
    const float* wep = Wel + h * 128 + dbase;
    float qwe;
    {
        float4 wa = *(const float4*)wep;
        float4 wb = *(const float4*)(wep + 4);
        qwe = wred16((float)qh[0] * wa.x + (float)qh[1] * wa.y + (float)qh[2] * wa.z + (float)qh[3] * wa.w +
                     (float)qh[4] * wb.x + (float)qh[5] * wb.y + (float)qh[6] * wb.z + (float)qh[7] * wb.w);
    }

    float s0 = 0.f, s1 = 0.f, sea0 = 0.f, sea1 = 0.f;
    float a0[8] = {0.f, 0.f, 0.f, 0.f, 0.f, 0.f, 0.f, 0.f};
    float a1[8] = {0.f, 0.f, 0.f, 0.f, 0.f, 0.f, 0.f, 0.f};

    int end = row_state[n];
    int beg = (n > 0) ? row_state[n - 1] : 0;
    int nit = (end - beg + 7) >> 3;
    int lbase = (h << 7) + (sl << 3);

    int2 cA, cB, cC, cD;
    if (nit > 0) {
        int e = beg + slot;
        cA = csr[(e < end) ? e : beg];
        cB = csr[(e + 2 < end) ? e + 2 : beg];
        cC = csr[(e + 4 < end) ? e + 4 : beg];
        cD = csr[(e + 6 < end) ? e + 6 : beg];
    }

    for (int it = 0; it < nit; ++it) {
        int ebase = beg + 8 * it + slot;
        bool vA = ebase < end, vB = ebase + 2 < end, vC = ebase + 4 < end, vD = ebase + 6 < end;
        float eaA = __int_as_float(cA.y);
        float eaB = __int_as_float(cB.y);
        float eaC = __int_as_float(cC.y);
        float eaD = __int_as_float(cD.y);
        int koA = (cA.x << 9) + lbase;
        int koB = (cB.x << 9) + lbase;
        int koC = (cC.x << 9) + lbase;
        int koD = (cD.x << 9) + lbase;
        half8v kA = *(const half8v*)(kvh + koA);
        half8v kB = *(const half8v*)(kvh + koB);
        half8v kC = *(const half8v*)(kvh + koC);
        half8v kD = *(const half8v*)(kvh + koD);
        half8v vA8 = *(const half8v*)(kvh + koA + 256);
        half8v vB8 = *(const half8v*)(kvh + koB + 256);
        half8v vC8 = *(const half8v*)(kvh + koC + 256);
        half8v vD8 = *(const half8v*)(kvh + koD + 256);
        __builtin_amdgcn_sched_barrier(0);
        if (it + 1 < nit) {
            int e2 = ebase + 8;
            cA = csr[(e2 < end) ? e2 : beg];
            cB = csr[(e2 + 2 < end) ? e2 + 2 : beg];
            cC = csr[(e2 + 4 < end) ? e2 + 4 : beg];
            cD = csr[(e2 + 6 < end) ? e2 + 6 : beg];
        }

        H2U ka, kb, kc, kd;
        ka.v = kA; kb.v = kB; kc.v = kC; kd.v = kD;
        float dA0 = __builtin_amdgcn_fdot2(qq.h[0], ka.h[0], 0.f, false);
        float dA1 = __builtin_amdgcn_fdot2(qq.h[1], ka.h[1], 0.f, false);
        dA0 = __builtin_amdgcn_fdot2(qq.h[2], ka.h[2], dA0, false);
        dA1 = __builtin_amdgcn_fdot2(qq.h[3], ka.h[3], dA1, false);
        float dB0 = __builtin_amdgcn_fdot2(qq.h[0], kb.h[0], 0.f, false);
        float dB1 = __builtin_amdgcn_fdot2(qq.h[1], kb.h[1], 0.f, false);
        dB0 = __builtin_amdgcn_fdot2(qq.h[2], kb.h[2], dB0, false);
        dB1 = __builtin_amdgcn_fdot2(qq.h[3], kb.h[3], dB1, false);
        float dC0 = __builtin_amdgcn_fdot2(qq.h[0], kc.h[0], 0.f, false);
        float dC1 = __builtin_amdgcn_fdot2(qq.h[1], kc.h[1], 0.f, false);
        dC0 = __builtin_amdgcn_fdot2(qq.h[2], kc.h[2], dC0, false);
        dC1 = __builtin_amdgcn_fdot2(qq.h[3], kc.h[3], dC1, false);
        float dD0 = __builtin_amdgcn_fdot2(qq.h[0], kd.h[0], 0.f, false);
        float dD1 = __builtin_amdgcn_fdot2(qq.h[1], kd.h[1], 0.f, false);
        dD0 = __builtin_amdgcn_fdot2(qq.h[2], kd.h[2], dD0, false);
        dD1 = __builtin_amdgcn_fdot2(qq.h[3], kd.h[3], dD1, false);
        float pA = wred16(dA0 + dA1);
        float pB = wred16(dB0 + dB1);
        float pC = wred16(dC0 + dC1);
        float pD = wred16(dD0 + dD1);
        float wA = vA ? fexp2(fmaf(eaA, qwe, pA)) : 0.f;
        float wB = vB ? fexp2(fmaf(eaB, qwe, pB)) : 0.f;
        float wC = vC ? fexp2(fmaf(eaC, qwe, pC)) : 0.f;
        float wD = vD ? fexp2(fmaf(eaD, qwe, pD)) : 0.f;
        s0 += wA; s1 += wB; s0 += wC; s1 += wD;
        sea0 = fmaf(wA, eaA, sea0);
        sea1 = fmaf(wB, eaB, sea1);
        sea0 = fmaf(wC, eaC, sea0);
        sea1 = fmaf(wD, eaD, sea1);
        #pragma unroll
        for (int d = 0; d < 8; ++d) {
            a0[d] = fmaf(wA, (float)vA8[d], a0[d]);
            a1[d] = fmaf(wB, (float)vB8[d], a1[d]);
            a0[d] = fmaf(wC, (float)vC8[d], a0[d]);
            a1[d] = fmaf(wD, (float)vD8[d], a1[d]);
        }
    }

    float s = s0 + s1, sea = sea0 + sea1;
    float o0 = a0[0] + a1[0], o1 = a0[1] + a1[1], o2 = a0[2] + a1[2], o3 = a0[3] + a1[3];
    float o4 = a0[4] + a1[4], o5 = a0[5] + a1[5], o6 = a0[6] + a1[6], o7 = a0[7] + a1[7];

    s += __shfl_xor(s, 32, 64);
    sea += __shfl_xor(sea, 32, 64);
    o0 += __shfl_xor(o0, 32, 64);
    o1 += __shfl_xor(o1, 32, 64);
    o2 += __shfl_xor(o2, 32, 64);
    o3 += __shfl_xor(o3, 32, 64);
    o4 += __shfl_xor(o4, 32, 64);
    o5 += __shfl_xor(o5, 32, 64);
    o6 += __shfl_xor(o6, 32, 64);
    o7 += __shfl_xor(o7, 32, 64);

    float4 wea = *(const float4*)wep;
    float4 web = *(const float4*)(wep + 4);

    float inv = (s > 0.f) ? 1.f / s : 1.f;
    float sw = sea * inv;
    o0 = o0 * inv + sw * wea.x;
    o1 = o1 * inv + sw * wea.y;
    o2 = o2 * inv + sw * wea.z;
    o3 = o3 * inv + sw * wea.w;
    o4 = o4 * inv + sw * web.x;
    o5 = o5 * inv + sw * web.y;
    o6 = o6 * inv + sw * web.z;
    o7 = o7 * inv + sw * web.w;
    o0 = 0.5f * (o0 + __shfl_xor(o0, 16, 64));
    o1 = 0.5f * (o1 + __shfl_xor(o1, 16, 64));
    o2 = 0.5f * (o2 + __shfl_xor(o2, 16, 64));
    o3 = 0.5f * (o3 + __shfl_xor(o3, 16, 64));
    o4 = 0.5f * (o4 + __shfl_xor(o4, 16, 64));
    o5 = 0.5f * (o5 + __shfl_xor(o5, 16, 64));
    o6 = 0.5f * (o6 + __shfl_xor(o6, 16, 64));
    o7 = 0.5f * (o7 + __shfl_xor(o7, 16, 64));

    const _Float16* skp = (const _Float16*)skipbuf + n * 128 + dbase;
    half8v skh = *(const half8v*)skp;
    const float* xrp = xcur + n * 128 + dbase;
    float4 xra = *(const float4*)xrp, xrb = *(const float4*)(xrp + 4);
    float y0 = o0 + (float)skh[0], y1 = o1 + (float)skh[1], y2 = o2 + (float)skh[2], y3 = o3 + (float)skh[3];
    float y4 = o4 + (float)skh[4], y5 = o5 + (float)skh[5], y6 = o6 + (float)skh[6], y7 = o7 + (float)skh[7];
    y0 = (y0 > 0.f) ? y0 : __expf(y0) - 1.f;
    y1 = (y1 > 0.f) ? y1 : __expf(y1) - 1.f;
    y2 = (y2 > 0.f) ? y2 : __expf(y2) - 1.f;
    y3 = (y3 > 0.f) ? y3 : __expf(y3) - 1.f;
    y4 = (y4 > 0.f) ? y4 : __expf(y4) - 1.f;
    y5 = (y5 > 0.f) ? y5 : __expf(y5) - 1.f;
    y6 = (y6 > 0.f) ? y6 : __expf(y6) - 1.f;
    y7 = (y7 > 0.f) ? y7 : __expf(y7) - 1.f;
    float p0 = xra.x + y0, p1 = xra.y + y1, p2 = xra.z + y2, p3 = xra.w + y3;
    float p4 = xrb.x + y4, p5 = xrb.y + y5, p6 = xrb.z + y6, p7 = xrb.w + y7;
    float mu = wred16(p0 + p1 + p2 + p3 + p4 + p5 + p6 + p7) * (1.f / 128.f);
    float c0 = p0 - mu, c1 = p1 - mu, c2 = p2 - mu, c3 = p3 - mu;
    float c4 = p4 - mu, c5 = p5 - mu, c6 = p6 - mu, c7 = p7 - mu;
    float var = wred16(c0 * c0 + c1 * c1 + c2 * c2 + c3 * c3 +
                       c4 * c4 + c5 * c5 + c6 * c6 + c7 * c7) * (1.f / 128.f);
    float r = rsqrtf(var + 1e-5f);
    if (lane < 16) {
        const float* gp = g + dbase;
        const float* bp = beta + dbase;
        float4 ga = *(const float4*)gp, gb = *(const float4*)(gp + 4);
        float4 ba = *(const float4*)bp, bb = *(const float4*)(bp + 4);
        float4 oa, ob;
        oa.x = c0 * r * ga.x + ba.x; oa.y = c1 * r * ga.y + ba.y;
        oa.z = c2 * r * ga.z + ba.z; oa.w = c3 * r * ga.w + ba.w;
        ob.x = c4 * r * gb.x + bb.x; ob.y = c5 * r * gb.y + bb.y;
        ob.z = c6 * r * gb.z + bb.z; ob.w = c7 * r * gb.w + bb.w;
        float* dp = dst + n * 128 + dbase;
        *(float4*)dp = oa;
        *(float4*)(dp + 4) = ob;
        if (xbout) {
            uint4 pk;
            pk.x = (unsigned)f2bf(oa.x) | ((unsigned)f2bf(oa.y) << 16);
            pk.y = (unsigned)f2bf(oa.z) | ((unsigned)f2bf(oa.w) << 16);
            pk.z = (unsigned)f2bf(ob.x) | ((unsigned)f2bf(ob.y) << 16);
            pk.w = (unsigned)f2bf(ob.z) | ((unsigned)f2bf(ob.w) << 16);
            *(uint4*)(xbout + n * 128 + dbase) = pk;
        }
    }
}

// ---------- launch ----------
extern "C" void kernel_launch(void* const* d_in, const int* in_sizes, int n_in,
                              void* d_out, int out_size, void* d_ws, size_t ws_size,
                              hipStream_t stream) {
    const float* x       = (const float*)d_in[0];
    const int*   ei      = (const int*)d_in[1];
    const float* eattr   = (const float*)d_in[2];
    const float* ln_in_g = (const float*)d_in[3];
    const float* ln_in_b = (const float*)d_in[4];
    const float* Wq = (const float*)d_in[5];
    const float* bq = (const float*)d_in[6];
    const float* Wk = (const float*)d_in[7];
    const float* bk = (const float*)d_in[8];
    const float* Wv = (const float*)d_in[9];
    const float* bv = (const float*)d_in[10];
    const float* We = (const float*)d_in[11];
    const float* Ws = (const float*)d_in[12];
    const float* bs = (const float*)d_in[13];
    const float* ln_g = (const float*)d_in[14];
    const float* ln_b = (const float*)d_in[15];
    float* out = (float*)d_out;

    char* p = (char*)d_ws;
    auto carve = [&](size_t bytes) {
        char* r = p;
        p += (bytes + 255) & ~(size_t)255;
        return (void*)r;
    };
    int*  cnt       = (int*)carve((size_t)NN * 4);
    int*  row_state = (int*)carve((size_t)NN * 4);
    int*  bsums     = (int*)carve(1024);
    int2* csr       = (int2*)carve((size_t)NE * 8);
    unsigned short* WcatT = (unsigned short*)carve((size_t)NLAYERS * MCOLS * HIDS * 2);
    float* bcat     = (float*)carve((size_t)NLAYERS * MCOLS * 4);
    float* xcur     = (float*)carve((size_t)NN * HIDS * 4);
    unsigned short* qpack  = (unsigned short*)carve((size_t)NN * 256 * 2);
    unsigned short* kvpack = (unsigned short*)carve((size_t)NN * 512 * 2);
    unsigned short* skipbuf = (unsigned short*)carve((size_t)NN * HIDS * 2);
    unsigned short* xb = (unsigned short*)carve((size_t)NN * HIDS * 2);

    const int NB_N = (NN + 255) / 256;        // 196
    const int NODE_BLOCKS = (NN + 3) / 4;     // 12500

    // K_A: ln_in | count | packw (independent; one launch)
    hipMemsetAsync(cnt, 0, (size_t)NN * 4, stream);
    eatb_fuseA<<<LNB + CNTB + PKWB, 256, 0, stream>>>(x, ln_in_g, ln_in_b, xcur, xb,
                                                      ei + NE, cnt,
                                                      Wq, Wk, Wv, Ws, bq, bk, bv, bs, WcatT, bcat);

    // CSR scan chain (small)
    eatb_blocksum<<<NB_N, 256, 0, stream>>>(cnt, bsums);
    eatb_scanb<<<1, 256, 0, stream>>>(bsums, NB_N);
    eatb_rowstart<<<NB_N, 256, 0, stream>>>(cnt, bsums, row_state);

    // K_E: gemm layer-0 | scatter (independent; scatter hides under gemm)
    eatb_fuseE<<<GEMM_BLOCKS + CNTB, 256, 0, stream>>>(xb, WcatT, bcat, qpack, kvpack, skipbuf,
                                                       ei, ei + NE, eattr, row_state, csr);

    // layers
    for (int l = 0; l < NLAYERS; ++l) {
        if (l > 0) {
            eatb_gemm<<<GEMM_BLOCKS, 256, 0, stream>>>(xb, WcatT + (size_t)l * MCOLS * HIDS,
                                                       bcat + (size_t)l * MCOLS, qpack, kvpack, skipbuf);
        }
        float* dst = (l == NLAYERS - 1) ? out : xcur;
        unsigned short* xbo = (l == NLAYERS - 1) ? nullptr : xb;
        eatb_attn<<<NODE_BLOCKS, 256, 0, stream>>>(qpack, kvpack, skipbuf, csr, row_state,
                                                   We + (size_t)l * 256, ln_g + (size_t)l * 128,
                                                   ln_b + (size_t)l * 128, xcur, dst, xbo);
    }
    (void)in_sizes; (void)n_in; (void)out_size; (void)ws_size;
}